// Round 13
// baseline (508.755 us; speedup 1.0000x reference)
//
#include <hip/hip_runtime.h>
#include <hip/hip_fp16.h>
#include <math.h>

// Problem constants (from reference)
#define Bn 8
#define Cn 32
#define Hn 120
#define Wn 160
#define HW (Hn*Wn)          // 19200
#define CHW (Cn*HW)         // 614400
#define OUTB (12 + CHW)     // 614412 floats per batch
#define DAMP_C 1e-4
#define OCC_THRES_C 0.1f

#define NCG 2               // channel groups
#define CPG (Cn/NCG)        // 16 channels per group
#define BPB (HW/256)        // 75 pixel-blocks per (batch, channel-group)

#define TPX 64              // pixels per prep tile
#define NTILE (HW/TPX)      // 300

// 16B load/store helper
union H8 { ulonglong2 q; __half h[8]; };

// ---------------------------------------------------------------------------
// prep: fused init (block 0) + sobel + fp16 cast + transpose to split-group
// planar layout [b][cg][p][16ch].
// Vectorized: thread = (4-pixel group, channel pair); per channel one float4
// row load + 2 clamped scalars per row (10 VMEM / 4 outputs, vs 40 scalar).
// LDS transpose write phase: 16B stores, a wave writes 1KB contiguous per
// array — no partial-line global writes (round-5 lesson); split-group keeps
// every 64B line private to one accum block (round-6 XCD lesson).
// ---------------------------------------------------------------------------
__global__ __launch_bounds__(256) void prep_kernel(
    const float* __restrict__ F1, const float* __restrict__ F0,
    const float* __restrict__ R_in, const float* __restrict__ t_in,
    __half* __restrict__ F1t, __half* __restrict__ F0t,
    __half* __restrict__ Gxt, __half* __restrict__ Gyt,
    float* __restrict__ pose, float* __restrict__ accum,
    unsigned int* __restrict__ counter)
{
    if (blockIdx.x == 0) {                       // fused init
        int b = threadIdx.x;
        if (b < Bn) {
            for (int i = 0; i < 9; ++i) pose[b*12 + i] = R_in[b*9 + i];
            for (int i = 0; i < 3; ++i) pose[b*12 + 9 + i] = t_in[b*3 + i];
            for (int i = 0; i < 32; ++i) accum[b*32 + i] = 0.0f;
        }
        if (threadIdx.x == 0) *counter = 0u;
    }
    __shared__ __align__(16) __half sF1[TPX][40];   // 80B rows: 16B-aligned reads
    __shared__ __align__(16) __half sF0[TPX][40];
    __shared__ __align__(16) __half sGx[TPX][40];
    __shared__ __align__(16) __half sGy[TPX][40];
    int tile = blockIdx.x % NTILE;
    int b    = blockIdx.x / NTILE;
    int p0 = tile * TPX;
    int xg = threadIdx.x & 15;          // 4-pixel group within tile
    int cp = threadIdx.x >> 4;          // 0..15 -> channels 2cp, 2cp+1
    int pg = p0 + xg*4;                 // first pixel of group (4 | pg, same row)
    int y = pg / Wn, x = pg % Wn;
    int ym = max(y-1,0)*Wn, yc = y*Wn, yp = min(y+1,Hn-1)*Wn;
    int xl = max(x-1,0), xr = min(x+4,Wn-1);
    #pragma unroll
    for (int cc = 0; cc < 2; ++cc) {
        int c = cp*2 + cc;
        const float* Fp = F1 + ((size_t)b*Cn + c)*HW;
        float4 r0 = *reinterpret_cast<const float4*>(Fp + ym + x);
        float4 r1 = *reinterpret_cast<const float4*>(Fp + yc + x);
        float4 r2 = *reinterpret_cast<const float4*>(Fp + yp + x);
        float l0 = Fp[ym+xl], q0 = Fp[ym+xr];
        float l1 = Fp[yc+xl], q1 = Fp[yc+xr];
        float l2 = Fp[yp+xl], q2 = Fp[yp+xr];
        float4 f0v = *reinterpret_cast<const float4*>(F0 + ((size_t)b*Cn + c)*HW + pg);
        float a0[6] = {l0, r0.x, r0.y, r0.z, r0.w, q0};
        float a1[6] = {l1, r1.x, r1.y, r1.z, r1.w, q1};
        float a2[6] = {l2, r2.x, r2.y, r2.z, r2.w, q2};
        float f0a[4] = {f0v.x, f0v.y, f0v.z, f0v.w};
        #pragma unroll
        for (int j = 0; j < 4; ++j) {
            float dx = (a0[j+2]-a0[j]) + 2.0f*(a1[j+2]-a1[j]) + (a2[j+2]-a2[j]);
            float dy = (a2[j]-a0[j]) + 2.0f*(a2[j+1]-a0[j+1]) + (a2[j+2]-a0[j+2]);
            float mag = sqrtf(dx*dx + dy*dy + 1e-8f);
            int px = xg*4 + j;
            sGx[px][c] = __float2half(dx / mag);
            sGy[px][c] = __float2half(dy / mag);
            sF1[px][c] = __float2half(a1[j+1]);
            sF0[px][c] = __float2half(f0a[j]);
        }
    }
    __syncthreads();
    int cq = threadIdx.x >> 7;           // 0..1 channel group (16ch)
    int pi = (threadIdx.x >> 1) & 63;    // pixel
    int hq = threadIdx.x & 1;            // which 8-half of the 16-ch group
    int so = cq*16 + hq*8;
    H8 of1, of0, ogx, ogy;
    of1.q = *reinterpret_cast<const ulonglong2*>(&sF1[pi][so]);
    of0.q = *reinterpret_cast<const ulonglong2*>(&sF0[pi][so]);
    ogx.q = *reinterpret_cast<const ulonglong2*>(&sGx[pi][so]);
    ogy.q = *reinterpret_cast<const ulonglong2*>(&sGy[pi][so]);
    size_t o = (((size_t)b*NCG + cq)*HW + p0 + pi)*CPG + hq*8;
    *reinterpret_cast<ulonglong2*>(F1t + o) = of1.q;
    *reinterpret_cast<ulonglong2*>(F0t + o) = of0.q;
    *reinterpret_cast<ulonglong2*>(Gxt + o) = ogx.q;
    *reinterpret_cast<ulonglong2*>(Gyt + o) = ogy.q;
}

// ---------------------------------------------------------------------------
// accum + tail-block solve. One block = 256 pixels x 16 channels.
// Grid = Bn*NCG*BPB = 1200. 26 independent 16B loads up-front (MLP).
// Last-arriving block (device-scope counter) performs the 6x6 damped solve,
// se3_exp, pose update, accum/counter reset — removes 3 solve launches.
// No spinning -> deadlock-free under any dispatch order (G16).
// ---------------------------------------------------------------------------
template<bool LAST>
__global__ __launch_bounds__(256, 2) void accum_kernel(
    const float* __restrict__ invD0, const float* __restrict__ invD1,
    const float* __restrict__ Kin,
    const __half* __restrict__ F1t, const __half* __restrict__ F0t,
    const __half* __restrict__ Gxt, const __half* __restrict__ Gyt,
    float* __restrict__ pose, float* __restrict__ accum,
    unsigned int* __restrict__ counter,
    float* __restrict__ out)
{
    __shared__ float sp[16];
    __shared__ float sred[4*27];
    __shared__ unsigned int sdone;
    int blk = blockIdx.x;
    int pblk = blk % BPB;
    int cg   = (blk / BPB) % NCG;
    int b    = blk / (BPB * NCG);
    int p = pblk * 256 + threadIdx.x;
    if (threadIdx.x < 12) sp[threadIdx.x] = pose[b*12 + threadIdx.x];
    else if (threadIdx.x < 16) sp[threadIdx.x] = Kin[b*4 + threadIdx.x - 12];
    __syncthreads();
    float R0=sp[0],R1=sp[1],R2=sp[2],R3=sp[3],R4=sp[4],R5=sp[5],R6=sp[6],R7=sp[7],R8=sp[8];
    float t0=sp[9],t1=sp[10],t2=sp[11];
    float fx=sp[12],fy=sp[13],cx=sp[14],cy=sp[15];

    int y = p / Wn, x = p % Wn;
    float px = ((float)x - cx) / fx;
    float py = ((float)y - cy) / fy;
    float d = invD0[(size_t)b*HW + p];

    // _warp_inverse_depth: warped = R@[px,py,1] + t*d   (all f32)
    float X = R0*px + R1*py + R2 + t0*d;
    float Y = R3*px + R4*py + R5 + t1*d;
    float S = R6*px + R7*py + R8 + t2*d;
    float u = X / S * fx + cx;
    float v = Y / S * fy + cy;
    float iz = d / S;
    bool inview = (u > 0.0f) && (u < (float)(Wn-1)) && (v > 0.0f) && (v < (float)(Hn-1));

    float uc = fminf(fmaxf(u, 0.0f), (float)(Wn-1));
    float vc = fminf(fmaxf(v, 0.0f), (float)(Hn-1));
    float x0f = floorf(uc), y0f = floorf(vc);
    float wx = uc - x0f, wy = vc - y0f;
    int x0 = (int)x0f, y0 = (int)y0f;
    int x1 = min(x0+1, Wn-1), y1 = min(y0+1, Hn-1);
    int i00 = y0*Wn + x0, i01 = y0*Wn + x1, i10 = y1*Wn + x0, i11 = y1*Wn + x1;
    float w00 = (1.0f-wx)*(1.0f-wy), w01 = wx*(1.0f-wy);
    float w10 = (1.0f-wx)*wy,        w11 = wx*wy;

    const float* iD1 = invD1 + (size_t)b*HW;
    float invD1w = iD1[i00]*w00 + iD1[i01]*w01 + iD1[i10]*w10 + iD1[i11]*w11;
    bool occ = !((iz > invD1w - OCC_THRES_C) && inview);

    // _jacobian_warping: warped = R@[px,py,d] + t
    float xj  = R0*px + R1*py + R2*d + t0;
    float yj  = R3*px + R4*py + R5*d + t1;
    float izj = R6*px + R7*py + R8*d + t2;
    float Jx[6], Jy[6];
    Jx[0] = -xj*yj*fx;        Jx[1] = (1.0f + xj*xj)*fx; Jx[2] = -yj*fx;
    Jx[3] = izj*fx;           Jx[4] = 0.0f;              Jx[5] = -izj*xj*fx;
    Jy[0] = -(1.0f + yj*yj)*fy; Jy[1] = xj*yj*fy;        Jy[2] = xj*fy;
    Jy[3] = 0.0f;             Jy[4] = izj*fy;            Jy[5] = -izj*yj*fy;

    // ---- vector-load phase: 26 x 16B independent loads (MLP) ----
    size_t gbase = ((size_t)b*NCG + cg)*HW*CPG;
    const __half* F1g = F1t + gbase;
    const __half* F0g = F0t + gbase;
    const __half* Gxg = Gxt + gbase;
    const __half* Gyg = Gyt + gbase;
    size_t t00 = (size_t)i00*CPG, t01 = (size_t)i01*CPG;
    size_t t10 = (size_t)i10*CPG, t11 = (size_t)i11*CPG;
    H8 f00[2], f01[2], f10[2], f11[2], ff0[2];
    H8 gx00[2], gx01[2], gx10[2], gx11[2];
    H8 gy00[2], gy01[2], gy10[2], gy11[2];
    #pragma unroll
    for (int h = 0; h < 2; ++h) {
        f00[h].q  = *reinterpret_cast<const ulonglong2*>(F1g + t00 + h*8);
        f01[h].q  = *reinterpret_cast<const ulonglong2*>(F1g + t01 + h*8);
        f10[h].q  = *reinterpret_cast<const ulonglong2*>(F1g + t10 + h*8);
        f11[h].q  = *reinterpret_cast<const ulonglong2*>(F1g + t11 + h*8);
        gx00[h].q = *reinterpret_cast<const ulonglong2*>(Gxg + t00 + h*8);
        gx01[h].q = *reinterpret_cast<const ulonglong2*>(Gxg + t01 + h*8);
        gx10[h].q = *reinterpret_cast<const ulonglong2*>(Gxg + t10 + h*8);
        gx11[h].q = *reinterpret_cast<const ulonglong2*>(Gxg + t11 + h*8);
        gy00[h].q = *reinterpret_cast<const ulonglong2*>(Gyg + t00 + h*8);
        gy01[h].q = *reinterpret_cast<const ulonglong2*>(Gyg + t01 + h*8);
        gy10[h].q = *reinterpret_cast<const ulonglong2*>(Gyg + t10 + h*8);
        gy11[h].q = *reinterpret_cast<const ulonglong2*>(Gyg + t11 + h*8);
        ff0[h].q  = *reinterpret_cast<const ulonglong2*>(F0g + (size_t)p*CPG + h*8);
    }

    // ---- compute phase: 16 channels ----
    int co = cg * CPG;
    float A2 = 0.0f, B2 = 0.0f, ABc = 0.0f, Sx = 0.0f, Sy = 0.0f;
    #pragma unroll
    for (int ccv = 0; ccv < CPG; ++ccv) {
        int h = ccv >> 3, k = ccv & 7;
        float f1w = __half2float(f00[h].h[k])*w00 + __half2float(f01[h].h[k])*w01
                  + __half2float(f10[h].h[k])*w10 + __half2float(f11[h].h[k])*w11;
        float gx  = __half2float(gx00[h].h[k])*w00 + __half2float(gx01[h].h[k])*w01
                  + __half2float(gx10[h].h[k])*w10 + __half2float(gx11[h].h[k])*w11;
        float gy  = __half2float(gy00[h].h[k])*w00 + __half2float(gy01[h].h[k])*w01
                  + __half2float(gy10[h].h[k])*w10 + __half2float(gy11[h].h[k])*w11;
        float r = occ ? 0.001f : (f1w - __half2float(ff0[h].h[k]));
        float wt = 1.0f / (1.0f + r*r);
        if (LAST) __builtin_nontemporal_store(wt, &out[(size_t)b*OUTB + 12 + (co+ccv)*HW + p]);
        A2 += gx*gx; B2 += gy*gy; ABc += gx*gy;
        float wr = wt * r;
        Sx += wr*gx; Sy += wr*gy;
    }

    // per-pixel 21 (sym JtJ) + 6 (rhs) partials (linear in the 5 sums)
    float part[27];
    {
        int idx = 0;
        #pragma unroll
        for (int k = 0; k < 6; ++k)
            #pragma unroll
            for (int l = k; l < 6; ++l)
                part[idx++] = A2*Jx[k]*Jx[l] + ABc*(Jx[k]*Jy[l] + Jy[k]*Jx[l]) + B2*Jy[k]*Jy[l];
        #pragma unroll
        for (int k = 0; k < 6; ++k) part[21+k] = -(Sx*Jx[k] + Sy*Jy[k]);
    }

    // wave64 shuffle reduce, cross-wave LDS reduce, one atomicAdd per entry
    #pragma unroll
    for (int i = 0; i < 27; ++i) {
        float vsum = part[i];
        for (int off = 32; off > 0; off >>= 1) vsum += __shfl_down(vsum, off, 64);
        part[i] = vsum;
    }
    int lane = threadIdx.x & 63, wave = threadIdx.x >> 6;
    if (lane == 0)
        for (int i = 0; i < 27; ++i) sred[wave*27 + i] = part[i];
    __syncthreads();
    if (threadIdx.x < 27) {
        float s = sred[threadIdx.x] + sred[27+threadIdx.x] + sred[54+threadIdx.x] + sred[81+threadIdx.x];
        atomicAdd(&accum[b*32 + threadIdx.x], s);
    }

    // ---- tail-block solve ----
    __threadfence();                         // order accum atomics before counter
    __syncthreads();
    if (threadIdx.x == 0) sdone = atomicAdd(counter, 1u);
    __syncthreads();
    if (sdone != (unsigned)(gridDim.x - 1)) return;
    __threadfence();                         // acquire: all blocks' adds visible
    int bb = threadIdx.x;
    if (bb == 0) atomicExch(counter, 0u);    // ready for next iteration
    if (bb >= Bn) return;
    float acc[27];
    for (int i = 0; i < 27; ++i) acc[i] = atomicAdd(&accum[bb*32 + i], 0.0f);
    for (int i = 0; i < 27; ++i) atomicExch(&accum[bb*32 + i], 0.0f);
    double A[6][7];
    {
        int idx = 0;
        for (int k = 0; k < 6; ++k)
            for (int l = k; l < 6; ++l) {
                double vv = (double)acc[idx++];
                A[k][l] = vv; A[l][k] = vv;
            }
        for (int k = 0; k < 6; ++k) { A[k][k] += DAMP_C; A[k][6] = (double)acc[21+k]; }
    }
    for (int col = 0; col < 6; ++col) {      // GE with partial pivoting
        int piv = col;
        double mx = fabs(A[col][col]);
        for (int r = col+1; r < 6; ++r) { double a = fabs(A[r][col]); if (a > mx) { mx = a; piv = r; } }
        if (piv != col)
            for (int j = col; j < 7; ++j) { double tmp = A[col][j]; A[col][j] = A[piv][j]; A[piv][j] = tmp; }
        double inv = 1.0 / A[col][col];
        for (int r = col+1; r < 6; ++r) {
            double f = A[r][col] * inv;
            for (int j = col; j < 7; ++j) A[r][j] -= f * A[col][j];
        }
    }
    double dp[6];
    for (int col = 5; col >= 0; --col) {
        double s = A[col][6];
        for (int j = col+1; j < 6; ++j) s -= A[col][j] * dp[j];
        dp[col] = s / A[col][col];
    }
    // se3_exp (transcendentals via f32 HW ops; reference is f32 math)
    double w0 = dp[0], w1 = dp[1], w2 = dp[2];
    double v0 = dp[3], v1 = dp[4], v2 = dp[5];
    double th2 = w0*w0 + w1*w1 + w2*w2;
    double th = sqrt(th2 + 1e-12);
    float thf = (float)th;
    double sth = (double)sinf(thf);
    double cth = (double)cosf(thf);
    double a = sth / th;
    double bbv = (1.0 - cth) / (th2 + 1e-12);
    double ccv2 = (1.0 - a) / (th2 + 1e-12);
    double wxm[3][3] = {{0,-w2,w1},{w2,0,-w0},{-w1,w0,0}};
    double wx2[3][3];
    for (int i = 0; i < 3; ++i)
        for (int j = 0; j < 3; ++j) {
            double s = 0;
            for (int k = 0; k < 3; ++k) s += wxm[i][k]*wxm[k][j];
            wx2[i][j] = s;
        }
    double dR[3][3], V[3][3];
    for (int i = 0; i < 3; ++i)
        for (int j = 0; j < 3; ++j) {
            double I = (i == j) ? 1.0 : 0.0;
            dR[i][j] = I + a*wxm[i][j] + bbv*wx2[i][j];
            V[i][j]  = I + bbv*wxm[i][j] + ccv2*wx2[i][j];
        }
    double dt[3];
    for (int i = 0; i < 3; ++i) dt[i] = V[i][0]*v0 + V[i][1]*v1 + V[i][2]*v2;
    double Ro[3][3], to[3];
    for (int i = 0; i < 9; ++i) Ro[i/3][i%3] = (double)pose[bb*12 + i];
    for (int i = 0; i < 3; ++i) to[i] = (double)pose[bb*12 + 9 + i];
    double tn[3], Rn[3][3];
    for (int i = 0; i < 3; ++i)
        tn[i] = dR[i][0]*to[0] + dR[i][1]*to[1] + dR[i][2]*to[2] + dt[i];
    for (int i = 0; i < 3; ++i)
        for (int j = 0; j < 3; ++j)
            Rn[i][j] = dR[i][0]*Ro[0][j] + dR[i][1]*Ro[1][j] + dR[i][2]*Ro[2][j];
    for (int i = 0; i < 9; ++i) pose[bb*12 + i] = (float)Rn[i/3][i%3];
    for (int i = 0; i < 3; ++i) pose[bb*12 + 9 + i] = (float)tn[i];
    if (LAST) {
        for (int i = 0; i < 9; ++i) out[(size_t)bb*OUTB + i] = (float)Rn[i/3][i%3];
        for (int i = 0; i < 3; ++i) out[(size_t)bb*OUTB + 9 + i] = (float)tn[i];
    }
}

// ---------------------------------------------------------------------------
extern "C" void kernel_launch(void* const* d_in, const int* in_sizes, int n_in,
                              void* d_out, int out_size, void* d_ws, size_t ws_size,
                              hipStream_t stream) {
    const float* R_in  = (const float*)d_in[0];
    const float* t_in  = (const float*)d_in[1];
    const float* F0    = (const float*)d_in[2];
    const float* F1    = (const float*)d_in[3];
    const float* invD0 = (const float*)d_in[4];
    const float* invD1 = (const float*)d_in[5];
    const float* Kin   = (const float*)d_in[6];
    float* out = (float*)d_out;

    // ws layout (split-group planar [b][cg][p][16], fp16):
    //   F1t | F0t | Gxt | Gyt (each half[B*CHW])
    //   | accum f32[B*32] | pose f32[B*12] | counter u32
    __half* F1t = (__half*)d_ws;
    __half* F0t = F1t + (size_t)Bn*CHW;
    __half* Gxt = F0t + (size_t)Bn*CHW;
    __half* Gyt = Gxt + (size_t)Bn*CHW;
    float* accum = (float*)(Gyt + (size_t)Bn*CHW);
    float* pose  = accum + Bn*32;
    unsigned int* counter = (unsigned int*)(pose + Bn*12);

    prep_kernel<<<Bn*NTILE, 256, 0, stream>>>(F1, F0, R_in, t_in,
                                              F1t, F0t, Gxt, Gyt,
                                              pose, accum, counter);
    accum_kernel<false><<<Bn*NCG*BPB, 256, 0, stream>>>(
        invD0, invD1, Kin, F1t, F0t, Gxt, Gyt, pose, accum, counter, out);
    accum_kernel<false><<<Bn*NCG*BPB, 256, 0, stream>>>(
        invD0, invD1, Kin, F1t, F0t, Gxt, Gyt, pose, accum, counter, out);
    accum_kernel<true><<<Bn*NCG*BPB, 256, 0, stream>>>(
        invD0, invD1, Kin, F1t, F0t, Gxt, Gyt, pose, accum, counter, out);
}

// Round 14
// 209.673 us; speedup vs baseline: 2.4264x; 2.4264x over previous
//
#include <hip/hip_runtime.h>
#include <hip/hip_fp16.h>
#include <math.h>

// Problem constants (from reference)
#define Bn 8
#define Cn 32
#define Hn 120
#define Wn 160
#define HW (Hn*Wn)          // 19200
#define CHW (Cn*HW)         // 614400
#define OUTB (12 + CHW)     // 614412 floats per batch
#define DAMP_C 1e-4
#define OCC_THRES_C 0.1f

#define NCG 2               // channel groups
#define CPG (Cn/NCG)        // 16 channels per group
#define BPB (HW/256)        // 75 pixel-blocks per (batch, channel-group)

#define TPX 64              // pixels per prep tile
#define NTILE (HW/TPX)      // 300

// 16B load/store helper
union H8 { ulonglong2 q; __half h[8]; };

// ---------------------------------------------------------------------------
// prep: fused init (block 0) + sobel + fp16 cast + transpose to split-group
// planar layout [b][cg][p][16ch]. (Round-13 lesson: do NOT fuse the solve
// into accum — the per-block device-scope __threadfence costs ~130us/dispatch
// in L2 writebacks on the 8-XCD part. Separate solve kernel is ~5us.)
// Vectorized: thread = (4-pixel group, channel pair); per channel one float4
// row load + 2 clamped scalars per row. LDS transpose write phase: 16B
// stores, a wave writes 1KB contiguous per array — no partial-line global
// writes (round-5 lesson); split-group keeps every 64B line private to one
// accum block (round-6 XCD lesson).
// ---------------------------------------------------------------------------
__global__ __launch_bounds__(256) void prep_kernel(
    const float* __restrict__ F1, const float* __restrict__ F0,
    const float* __restrict__ R_in, const float* __restrict__ t_in,
    __half* __restrict__ F1t, __half* __restrict__ F0t,
    __half* __restrict__ Gxt, __half* __restrict__ Gyt,
    float* __restrict__ pose, float* __restrict__ accum)
{
    if (blockIdx.x == 0) {                       // fused init
        int b = threadIdx.x;
        if (b < Bn) {
            for (int i = 0; i < 9; ++i) pose[b*12 + i] = R_in[b*9 + i];
            for (int i = 0; i < 3; ++i) pose[b*12 + 9 + i] = t_in[b*3 + i];
            for (int i = 0; i < 32; ++i) accum[b*32 + i] = 0.0f;
        }
    }
    __shared__ __align__(16) __half sF1[TPX][40];   // 80B rows: 16B-aligned reads
    __shared__ __align__(16) __half sF0[TPX][40];
    __shared__ __align__(16) __half sGx[TPX][40];
    __shared__ __align__(16) __half sGy[TPX][40];
    int tile = blockIdx.x % NTILE;
    int b    = blockIdx.x / NTILE;
    int p0 = tile * TPX;
    int xg = threadIdx.x & 15;          // 4-pixel group within tile
    int cp = threadIdx.x >> 4;          // 0..15 -> channels 2cp, 2cp+1
    int pg = p0 + xg*4;                 // first pixel of group (4 | pg, same row)
    int y = pg / Wn, x = pg % Wn;
    int ym = max(y-1,0)*Wn, yc = y*Wn, yp = min(y+1,Hn-1)*Wn;
    int xl = max(x-1,0), xr = min(x+4,Wn-1);
    #pragma unroll
    for (int cc = 0; cc < 2; ++cc) {
        int c = cp*2 + cc;
        const float* Fp = F1 + ((size_t)b*Cn + c)*HW;
        float4 r0 = *reinterpret_cast<const float4*>(Fp + ym + x);
        float4 r1 = *reinterpret_cast<const float4*>(Fp + yc + x);
        float4 r2 = *reinterpret_cast<const float4*>(Fp + yp + x);
        float l0 = Fp[ym+xl], q0 = Fp[ym+xr];
        float l1 = Fp[yc+xl], q1 = Fp[yc+xr];
        float l2 = Fp[yp+xl], q2 = Fp[yp+xr];
        float4 f0v = *reinterpret_cast<const float4*>(F0 + ((size_t)b*Cn + c)*HW + pg);
        float a0[6] = {l0, r0.x, r0.y, r0.z, r0.w, q0};
        float a1[6] = {l1, r1.x, r1.y, r1.z, r1.w, q1};
        float a2[6] = {l2, r2.x, r2.y, r2.z, r2.w, q2};
        float f0a[4] = {f0v.x, f0v.y, f0v.z, f0v.w};
        #pragma unroll
        for (int j = 0; j < 4; ++j) {
            float dx = (a0[j+2]-a0[j]) + 2.0f*(a1[j+2]-a1[j]) + (a2[j+2]-a2[j]);
            float dy = (a2[j]-a0[j]) + 2.0f*(a2[j+1]-a0[j+1]) + (a2[j+2]-a0[j+2]);
            float mag = sqrtf(dx*dx + dy*dy + 1e-8f);
            int px = xg*4 + j;
            sGx[px][c] = __float2half(dx / mag);
            sGy[px][c] = __float2half(dy / mag);
            sF1[px][c] = __float2half(a1[j+1]);
            sF0[px][c] = __float2half(f0a[j]);
        }
    }
    __syncthreads();
    int cq = threadIdx.x >> 7;           // 0..1 channel group (16ch)
    int pi = (threadIdx.x >> 1) & 63;    // pixel
    int hq = threadIdx.x & 1;            // which 8-half of the 16-ch group
    int so = cq*16 + hq*8;
    H8 of1, of0, ogx, ogy;
    of1.q = *reinterpret_cast<const ulonglong2*>(&sF1[pi][so]);
    of0.q = *reinterpret_cast<const ulonglong2*>(&sF0[pi][so]);
    ogx.q = *reinterpret_cast<const ulonglong2*>(&sGx[pi][so]);
    ogy.q = *reinterpret_cast<const ulonglong2*>(&sGy[pi][so]);
    size_t o = (((size_t)b*NCG + cq)*HW + p0 + pi)*CPG + hq*8;
    *reinterpret_cast<ulonglong2*>(F1t + o) = of1.q;
    *reinterpret_cast<ulonglong2*>(F0t + o) = of0.q;
    *reinterpret_cast<ulonglong2*>(Gxt + o) = ogx.q;
    *reinterpret_cast<ulonglong2*>(Gyt + o) = ogy.q;
}

// ---------------------------------------------------------------------------
// Main kernel: one block = 256 pixels x 16 channels. Grid = Bn*NCG*BPB = 1200.
// 26 independent 16B loads issued up-front per thread (MLP); launch_bounds
// (256,2) permits up to 256 VGPR so the compiler keeps them in flight.
// Ends at per-block atomicAdd — no fences (round-13 lesson).
// invD path stays f32 -> occlusion booleans bit-identical to reference.
// ---------------------------------------------------------------------------
template<bool LAST>
__global__ __launch_bounds__(256, 2) void accum_kernel(
    const float* __restrict__ invD0, const float* __restrict__ invD1,
    const float* __restrict__ Kin,
    const __half* __restrict__ F1t, const __half* __restrict__ F0t,
    const __half* __restrict__ Gxt, const __half* __restrict__ Gyt,
    const float* __restrict__ pose, float* __restrict__ accum,
    float* __restrict__ out)
{
    __shared__ float sp[16];
    __shared__ float sred[4*27];
    int blk = blockIdx.x;
    int pblk = blk % BPB;
    int cg   = (blk / BPB) % NCG;
    int b    = blk / (BPB * NCG);
    int p = pblk * 256 + threadIdx.x;
    if (threadIdx.x < 12) sp[threadIdx.x] = pose[b*12 + threadIdx.x];
    else if (threadIdx.x < 16) sp[threadIdx.x] = Kin[b*4 + threadIdx.x - 12];
    __syncthreads();
    float R0=sp[0],R1=sp[1],R2=sp[2],R3=sp[3],R4=sp[4],R5=sp[5],R6=sp[6],R7=sp[7],R8=sp[8];
    float t0=sp[9],t1=sp[10],t2=sp[11];
    float fx=sp[12],fy=sp[13],cx=sp[14],cy=sp[15];

    int y = p / Wn, x = p % Wn;
    float px = ((float)x - cx) / fx;
    float py = ((float)y - cy) / fy;
    float d = invD0[(size_t)b*HW + p];

    // _warp_inverse_depth: warped = R@[px,py,1] + t*d   (all f32)
    float X = R0*px + R1*py + R2 + t0*d;
    float Y = R3*px + R4*py + R5 + t1*d;
    float S = R6*px + R7*py + R8 + t2*d;
    float u = X / S * fx + cx;
    float v = Y / S * fy + cy;
    float iz = d / S;
    bool inview = (u > 0.0f) && (u < (float)(Wn-1)) && (v > 0.0f) && (v < (float)(Hn-1));

    float uc = fminf(fmaxf(u, 0.0f), (float)(Wn-1));
    float vc = fminf(fmaxf(v, 0.0f), (float)(Hn-1));
    float x0f = floorf(uc), y0f = floorf(vc);
    float wx = uc - x0f, wy = vc - y0f;
    int x0 = (int)x0f, y0 = (int)y0f;
    int x1 = min(x0+1, Wn-1), y1 = min(y0+1, Hn-1);
    int i00 = y0*Wn + x0, i01 = y0*Wn + x1, i10 = y1*Wn + x0, i11 = y1*Wn + x1;
    float w00 = (1.0f-wx)*(1.0f-wy), w01 = wx*(1.0f-wy);
    float w10 = (1.0f-wx)*wy,        w11 = wx*wy;

    const float* iD1 = invD1 + (size_t)b*HW;
    float invD1w = iD1[i00]*w00 + iD1[i01]*w01 + iD1[i10]*w10 + iD1[i11]*w11;
    bool occ = !((iz > invD1w - OCC_THRES_C) && inview);

    // _jacobian_warping: warped = R@[px,py,d] + t
    float xj  = R0*px + R1*py + R2*d + t0;
    float yj  = R3*px + R4*py + R5*d + t1;
    float izj = R6*px + R7*py + R8*d + t2;
    float Jx[6], Jy[6];
    Jx[0] = -xj*yj*fx;        Jx[1] = (1.0f + xj*xj)*fx; Jx[2] = -yj*fx;
    Jx[3] = izj*fx;           Jx[4] = 0.0f;              Jx[5] = -izj*xj*fx;
    Jy[0] = -(1.0f + yj*yj)*fy; Jy[1] = xj*yj*fy;        Jy[2] = xj*fy;
    Jy[3] = 0.0f;             Jy[4] = izj*fy;            Jy[5] = -izj*yj*fy;

    // ---- vector-load phase: 26 x 16B independent loads (MLP) ----
    size_t gbase = ((size_t)b*NCG + cg)*HW*CPG;
    const __half* F1g = F1t + gbase;
    const __half* F0g = F0t + gbase;
    const __half* Gxg = Gxt + gbase;
    const __half* Gyg = Gyt + gbase;
    size_t t00 = (size_t)i00*CPG, t01 = (size_t)i01*CPG;
    size_t t10 = (size_t)i10*CPG, t11 = (size_t)i11*CPG;
    H8 f00[2], f01[2], f10[2], f11[2], ff0[2];
    H8 gx00[2], gx01[2], gx10[2], gx11[2];
    H8 gy00[2], gy01[2], gy10[2], gy11[2];
    #pragma unroll
    for (int h = 0; h < 2; ++h) {
        f00[h].q  = *reinterpret_cast<const ulonglong2*>(F1g + t00 + h*8);
        f01[h].q  = *reinterpret_cast<const ulonglong2*>(F1g + t01 + h*8);
        f10[h].q  = *reinterpret_cast<const ulonglong2*>(F1g + t10 + h*8);
        f11[h].q  = *reinterpret_cast<const ulonglong2*>(F1g + t11 + h*8);
        gx00[h].q = *reinterpret_cast<const ulonglong2*>(Gxg + t00 + h*8);
        gx01[h].q = *reinterpret_cast<const ulonglong2*>(Gxg + t01 + h*8);
        gx10[h].q = *reinterpret_cast<const ulonglong2*>(Gxg + t10 + h*8);
        gx11[h].q = *reinterpret_cast<const ulonglong2*>(Gxg + t11 + h*8);
        gy00[h].q = *reinterpret_cast<const ulonglong2*>(Gyg + t00 + h*8);
        gy01[h].q = *reinterpret_cast<const ulonglong2*>(Gyg + t01 + h*8);
        gy10[h].q = *reinterpret_cast<const ulonglong2*>(Gyg + t10 + h*8);
        gy11[h].q = *reinterpret_cast<const ulonglong2*>(Gyg + t11 + h*8);
        ff0[h].q  = *reinterpret_cast<const ulonglong2*>(F0g + (size_t)p*CPG + h*8);
    }

    // ---- compute phase: 16 channels ----
    int co = cg * CPG;
    float A2 = 0.0f, B2 = 0.0f, ABc = 0.0f, Sx = 0.0f, Sy = 0.0f;
    #pragma unroll
    for (int ccv = 0; ccv < CPG; ++ccv) {
        int h = ccv >> 3, k = ccv & 7;
        float f1w = __half2float(f00[h].h[k])*w00 + __half2float(f01[h].h[k])*w01
                  + __half2float(f10[h].h[k])*w10 + __half2float(f11[h].h[k])*w11;
        float gx  = __half2float(gx00[h].h[k])*w00 + __half2float(gx01[h].h[k])*w01
                  + __half2float(gx10[h].h[k])*w10 + __half2float(gx11[h].h[k])*w11;
        float gy  = __half2float(gy00[h].h[k])*w00 + __half2float(gy01[h].h[k])*w01
                  + __half2float(gy10[h].h[k])*w10 + __half2float(gy11[h].h[k])*w11;
        float r = occ ? 0.001f : (f1w - __half2float(ff0[h].h[k]));
        float wt = 1.0f / (1.0f + r*r);
        if (LAST) __builtin_nontemporal_store(wt, &out[(size_t)b*OUTB + 12 + (co+ccv)*HW + p]);
        A2 += gx*gx; B2 += gy*gy; ABc += gx*gy;
        float wr = wt * r;
        Sx += wr*gx; Sy += wr*gy;
    }

    // per-pixel 21 (sym JtJ) + 6 (rhs) partials (linear in the 5 sums)
    float part[27];
    {
        int idx = 0;
        #pragma unroll
        for (int k = 0; k < 6; ++k)
            #pragma unroll
            for (int l = k; l < 6; ++l)
                part[idx++] = A2*Jx[k]*Jx[l] + ABc*(Jx[k]*Jy[l] + Jy[k]*Jx[l]) + B2*Jy[k]*Jy[l];
        #pragma unroll
        for (int k = 0; k < 6; ++k) part[21+k] = -(Sx*Jx[k] + Sy*Jy[k]);
    }

    // wave64 shuffle reduce, cross-wave LDS reduce, one atomicAdd per entry
    #pragma unroll
    for (int i = 0; i < 27; ++i) {
        float vsum = part[i];
        for (int off = 32; off > 0; off >>= 1) vsum += __shfl_down(vsum, off, 64);
        part[i] = vsum;
    }
    int lane = threadIdx.x & 63, wave = threadIdx.x >> 6;
    if (lane == 0)
        for (int i = 0; i < 27; ++i) sred[wave*27 + i] = part[i];
    __syncthreads();
    if (threadIdx.x < 27) {
        float s = sred[threadIdx.x] + sred[27+threadIdx.x] + sred[54+threadIdx.x] + sred[81+threadIdx.x];
        atomicAdd(&accum[b*32 + threadIdx.x], s);
    }
}

// ---------------------------------------------------------------------------
// 6x6 damped solve (fp64 GE + partial pivot), se3_exp (hw f32 sin/cos),
// pose update. One thread per batch. Zeroes accum for the next iteration.
// Separate launch (~5us warm) — measured cheaper than fence-based fusion.
// ---------------------------------------------------------------------------
__global__ void solve_kernel(float* __restrict__ pose, float* __restrict__ accum,
                             float* __restrict__ out, int write_out) {
    int b = threadIdx.x;
    if (b >= Bn) return;
    double A[6][7];
    {
        float acc[27];
        for (int i = 0; i < 27; ++i) acc[i] = accum[b*32 + i];
        int idx = 0;
        for (int k = 0; k < 6; ++k)
            for (int l = k; l < 6; ++l) {
                double vv = (double)acc[idx++];
                A[k][l] = vv; A[l][k] = vv;
            }
        for (int k = 0; k < 6; ++k) { A[k][k] += DAMP_C; A[k][6] = (double)acc[21+k]; }
        for (int i = 0; i < 32; ++i) accum[b*32 + i] = 0.0f;   // ready for next iter
    }
    for (int col = 0; col < 6; ++col) {      // GE with partial pivoting
        int piv = col;
        double mx = fabs(A[col][col]);
        for (int r = col+1; r < 6; ++r) { double a = fabs(A[r][col]); if (a > mx) { mx = a; piv = r; } }
        if (piv != col)
            for (int j = col; j < 7; ++j) { double tmp = A[col][j]; A[col][j] = A[piv][j]; A[piv][j] = tmp; }
        double inv = 1.0 / A[col][col];
        for (int r = col+1; r < 6; ++r) {
            double f = A[r][col] * inv;
            for (int j = col; j < 7; ++j) A[r][j] -= f * A[col][j];
        }
    }
    double dp[6];
    for (int col = 5; col >= 0; --col) {
        double s = A[col][6];
        for (int j = col+1; j < 6; ++j) s -= A[col][j] * dp[j];
        dp[col] = s / A[col][col];
    }
    // se3_exp (transcendentals via f32 HW ops; reference is f32 math)
    double w0 = dp[0], w1 = dp[1], w2 = dp[2];
    double v0 = dp[3], v1 = dp[4], v2 = dp[5];
    double th2 = w0*w0 + w1*w1 + w2*w2;
    double th = sqrt(th2 + 1e-12);
    float thf = (float)th;
    double sth = (double)sinf(thf);
    double cth = (double)cosf(thf);
    double a = sth / th;
    double bb = (1.0 - cth) / (th2 + 1e-12);
    double cc = (1.0 - a) / (th2 + 1e-12);
    double wxm[3][3] = {{0,-w2,w1},{w2,0,-w0},{-w1,w0,0}};
    double wx2[3][3];
    for (int i = 0; i < 3; ++i)
        for (int j = 0; j < 3; ++j) {
            double s = 0;
            for (int k = 0; k < 3; ++k) s += wxm[i][k]*wxm[k][j];
            wx2[i][j] = s;
        }
    double dR[3][3], V[3][3];
    for (int i = 0; i < 3; ++i)
        for (int j = 0; j < 3; ++j) {
            double I = (i == j) ? 1.0 : 0.0;
            dR[i][j] = I + a*wxm[i][j] + bb*wx2[i][j];
            V[i][j]  = I + bb*wxm[i][j] + cc*wx2[i][j];
        }
    double dt[3];
    for (int i = 0; i < 3; ++i) dt[i] = V[i][0]*v0 + V[i][1]*v1 + V[i][2]*v2;
    double Ro[3][3], to[3];
    for (int i = 0; i < 9; ++i) Ro[i/3][i%3] = (double)pose[b*12 + i];
    for (int i = 0; i < 3; ++i) to[i] = (double)pose[b*12 + 9 + i];
    double tn[3], Rn[3][3];
    for (int i = 0; i < 3; ++i)
        tn[i] = dR[i][0]*to[0] + dR[i][1]*to[1] + dR[i][2]*to[2] + dt[i];
    for (int i = 0; i < 3; ++i)
        for (int j = 0; j < 3; ++j)
            Rn[i][j] = dR[i][0]*Ro[0][j] + dR[i][1]*Ro[1][j] + dR[i][2]*Ro[2][j];
    for (int i = 0; i < 9; ++i) pose[b*12 + i] = (float)Rn[i/3][i%3];
    for (int i = 0; i < 3; ++i) pose[b*12 + 9 + i] = (float)tn[i];
    if (write_out) {
        for (int i = 0; i < 9; ++i) out[(size_t)b*OUTB + i] = (float)Rn[i/3][i%3];
        for (int i = 0; i < 3; ++i) out[(size_t)b*OUTB + 9 + i] = (float)tn[i];
    }
}

// ---------------------------------------------------------------------------
extern "C" void kernel_launch(void* const* d_in, const int* in_sizes, int n_in,
                              void* d_out, int out_size, void* d_ws, size_t ws_size,
                              hipStream_t stream) {
    const float* R_in  = (const float*)d_in[0];
    const float* t_in  = (const float*)d_in[1];
    const float* F0    = (const float*)d_in[2];
    const float* F1    = (const float*)d_in[3];
    const float* invD0 = (const float*)d_in[4];
    const float* invD1 = (const float*)d_in[5];
    const float* Kin   = (const float*)d_in[6];
    float* out = (float*)d_out;

    // ws layout (split-group planar [b][cg][p][16], fp16):
    //   F1t | F0t | Gxt | Gyt (each half[B*CHW])
    //   | accum f32[B*32] | pose f32[B*12]
    __half* F1t = (__half*)d_ws;
    __half* F0t = F1t + (size_t)Bn*CHW;
    __half* Gxt = F0t + (size_t)Bn*CHW;
    __half* Gyt = Gxt + (size_t)Bn*CHW;
    float* accum = (float*)(Gyt + (size_t)Bn*CHW);
    float* pose  = accum + Bn*32;

    prep_kernel<<<Bn*NTILE, 256, 0, stream>>>(F1, F0, R_in, t_in,
                                              F1t, F0t, Gxt, Gyt, pose, accum);

    for (int it = 0; it < 3; ++it) {
        bool last = (it == 2);
        if (last)
            accum_kernel<true><<<Bn*NCG*BPB, 256, 0, stream>>>(
                invD0, invD1, Kin, F1t, F0t, Gxt, Gyt, pose, accum, out);
        else
            accum_kernel<false><<<Bn*NCG*BPB, 256, 0, stream>>>(
                invD0, invD1, Kin, F1t, F0t, Gxt, Gyt, pose, accum, out);
        solve_kernel<<<1, 64, 0, stream>>>(pose, accum, out, last ? 1 : 0);
    }
}